// Round 12
// baseline (2270.271 us; speedup 1.0000x reference)
//
#include <hip/hip_runtime.h>
#include <math.h>

typedef unsigned int u32;
typedef unsigned short u16;
typedef unsigned long long u64;

#define NN 50000
#define NE 800000
#define TOPK 8
#define NB 196           // coarse buckets of 256 rows (196*256 = 50176 >= NN)
#define BCAP 4608        // bucket capacity: mean 4082 + ~8 sigma
#define CURSTRIDE 16     // cursor padding: one counter per 64B line
#define GTILES 782       // ceil(NN/64) gemm tiles == edge chunks of 1024

// ---------------- gemm + edge partition fused ----------------
// Block b: gemm tile b (rows b*64..+63) AND edge chunk b (1024 edges).
// R11 lessons applied:
//  * ws staged in 32-k halves -> LDS 35.4 KB -> 4 blocks/CU, all 782 blocks
//    co-resident (R11: 52 KB -> 3/CU + 3.05 tail = latency-bound 51.6 us).
//  * ws chunk XOR-swizzle: physical col = col ^ ((chunk&8)?4:0). Un-swizzled,
//    read chunks cx in {0,4,8,12} share banks 0-3 (32B stride -> half banks
//    idle, 4-way conflict, 4.7M cycles). Swizzled: 2 chunks/bank = free.
// Partition: LDS histogram (196 buckets), ONE padded global atomicAdd per
// (block,bucket) issued at the kk=64 point; return consumed only at the tail
// scatter (no mid-kernel vmcnt stall). cursor[] zeroed by prior memset.
__global__ __launch_bounds__(256) void gemm_k(const float* __restrict__ x,
                                              const float* __restrict__ W,
                                              const float* __restrict__ att,
                                              const int* __restrict__ ei,
                                              float* __restrict__ hbuf,
                                              float* __restrict__ s_i,
                                              float* __restrict__ s_j,
                                              int* __restrict__ cursor,
                                              u32* __restrict__ breg) {
    __shared__ float xst[64][68];     // [k][r] transposed, 17.4 KB
    __shared__ float ws[32][128];     // [k][c] half-chunk, swizzled, 16 KB
    __shared__ u32 cnt[NB];           // 784 B
    __shared__ u32 base[NB];          // 784 B   -> 35.4 KB total, 4 blocks/CU
    const int t = threadIdx.x;
    const int cx = t & 15;            // col group: cols cx*8..+7
    const int ry = t >> 4;            // row group: rows ry*4..+3
    const int rbase = blockIdx.x * 64;
    const int swz = (cx & 4) ? 4 : 0; // read-side ws swizzle

    // edge chunk loads first (oldest vm ops -> retire before first use)
    const int e0 = blockIdx.x * 1024 + t * 4;
    const bool ev = e0 < NE;
    int4 er = make_int4(0, 0, 0, 0), ec = make_int4(0, 0, 0, 0);
    if (ev) {
        er = *reinterpret_cast<const int4*>(ei + e0);
        ec = *reinterpret_cast<const int4*>(ei + NE + e0);
    }
    if (t < NB) cnt[t] = 0;

    int bk[4];
    u32 lrk[4] = {0, 0, 0, 0};
    u32 myBase = 0;

    float acc[4][8];
    #pragma unroll
    for (int i = 0; i < 4; ++i)
        #pragma unroll
        for (int j = 0; j < 8; ++j) acc[i][j] = 0.f;

    const int wq = t & 31;                      // ws write chunk id
    const int wcol = (wq * 4) ^ ((wq & 8) ? 4 : 0);  // swizzled write col

    for (int kk = 0; kk < 128; kk += 64) {
        if (kk) __syncthreads();
        // stage x chunk (all 64 k), transposed
        #pragma unroll
        for (int rr = ry; rr < 64; rr += 16) {
            int gr = rbase + rr;
            float4 v = make_float4(0.f, 0.f, 0.f, 0.f);
            if (gr < NN)
                v = *reinterpret_cast<const float4*>(x + (size_t)gr * 128 + kk + cx * 4);
            xst[cx * 4 + 0][rr] = v.x;
            xst[cx * 4 + 1][rr] = v.y;
            xst[cx * 4 + 2][rr] = v.z;
            xst[cx * 4 + 3][rr] = v.w;
        }

        for (int ks = 0; ks < 64; ks += 32) {
            if (ks) __syncthreads();   // protect previous ws-half reads
            #pragma unroll
            for (int wk = t >> 5; wk < 32; wk += 8) {
                float4 v = *reinterpret_cast<const float4*>(
                    W + (size_t)(kk + ks + wk) * 128 + wq * 4);
                *reinterpret_cast<float4*>(&ws[wk][wcol]) = v;
            }
            __syncthreads();

            if (kk == 0 && ks == 0) {
                if (ev) {      // LDS histogram (edges retired by staging drain)
                    int rows[4] = {er.x, er.y, er.z, er.w};
                    #pragma unroll
                    for (int i = 0; i < 4; ++i) {
                        bk[i] = rows[i] >> 8;
                        lrk[i] = atomicAdd(&cnt[bk[i]], 1u);
                    }
                }
            } else if (kk == 64 && ks == 0) {
                // histogram complete (barriers above); cursor atomics now —
                // return consumed only after the epilogue.
                if (t < NB && cnt[t] > 0)
                    myBase = (u32)atomicAdd(cursor + t * CURSTRIDE, (int)cnt[t]);
            }

            for (int k2 = 0; k2 < 32; ++k2) {
                float4 xa = *reinterpret_cast<const float4*>(&xst[ks + k2][ry * 4]);
                float4 wa = *reinterpret_cast<const float4*>(&ws[k2][(cx * 8) ^ swz]);
                float4 wb = *reinterpret_cast<const float4*>(&ws[k2][(cx * 8 + 4) ^ swz]);
                float xv[4] = {xa.x, xa.y, xa.z, xa.w};
                float wv[8] = {wa.x, wa.y, wa.z, wa.w, wb.x, wb.y, wb.z, wb.w};
                #pragma unroll
                for (int i = 0; i < 4; ++i)
                    #pragma unroll
                    for (int j = 0; j < 8; ++j) acc[i][j] += xv[i] * wv[j];
            }
        }
    }

    // epilogue: h + s_i/s_j (independent of the cursor atomics)
    const int head = cx >> 2;
    float aiv[8], ajv[8];
    #pragma unroll
    for (int j = 0; j < 8; ++j) {
        aiv[j] = att[head * 64 + (cx & 3) * 8 + j];
        ajv[j] = att[head * 64 + 32 + (cx & 3) * 8 + j];
    }
    #pragma unroll
    for (int i = 0; i < 4; ++i) {
        int gr = rbase + ry * 4 + i;
        float pi = 0.f, pj = 0.f;
        #pragma unroll
        for (int j = 0; j < 8; ++j) {
            pi += acc[i][j] * aiv[j];
            pj += acc[i][j] * ajv[j];
        }
        pi += __shfl_xor(pi, 1); pi += __shfl_xor(pi, 2);
        pj += __shfl_xor(pj, 1); pj += __shfl_xor(pj, 2);
        if (gr < NN) {
            float* dst = hbuf + (size_t)gr * 128 + cx * 8;
            *reinterpret_cast<float4*>(dst)     = make_float4(acc[i][0], acc[i][1], acc[i][2], acc[i][3]);
            *reinterpret_cast<float4*>(dst + 4) = make_float4(acc[i][4], acc[i][5], acc[i][6], acc[i][7]);
            if ((cx & 3) == 0) {
                s_i[(size_t)gr * 4 + head] = pi;
                s_j[(size_t)gr * 4 + head] = pj;
            }
        }
    }

    // publish bases (atomic returns have had the whole compute to land), scatter
    if (t < NB) base[t] = myBase;
    __syncthreads();
    if (ev) {
        int rows[4] = {er.x, er.y, er.z, er.w};
        int cols[4] = {ec.x, ec.y, ec.z, ec.w};
        #pragma unroll
        for (int i = 0; i < 4; ++i) {
            u32 pos = base[bk[i]] + lrk[i];
            if (pos < BCAP)
                breg[(size_t)bk[i] * BCAP + pos] = ((u32)(rows[i] & 255) << 16) | (u32)cols[i];
        }
    }
}

// ---------------- rowsel: LDS CSR build + top-k + softmax + aggregate ----------------
// 8 sub-blocks per bucket, 32 rows each, 128 threads -> grid 1568 (~6
// blocks/CU co-resident: R11's 784-block grid capped occupancy at 23% and
// rowsel stayed 51us; grid size, not LDS, was the limiter). All 128 threads
// active in top-k (1 thread per (row,head)). Block re-reads its bucket's
// packed edges (L2-hot) and filters its 32-row slice via bits 21-23.
// Key = sortable-float(s_j)<<32 | ~slot; slot tie-break exact (distinct-col
// ties measure-zero, same-col output-invariant, self-loop last among equals).
__global__ __launch_bounds__(128) void rowsel_k(const int* __restrict__ cursor,
                                                const u32* __restrict__ breg,
                                                const float* __restrict__ s_i,
                                                const float* __restrict__ s_j,
                                                const float* __restrict__ hbuf,
                                                float* __restrict__ out) {
    __shared__ u16 lcsr[32][66];        // 4.2 KB (pad 66: banking)
    __shared__ u32 ldeg[32];
    __shared__ float lal[128 * 8];      // 4 KB
    __shared__ u16  lcl[128 * 8];       // 2 KB
    const int t = threadIdx.x;
    const int B = blockIdx.x >> 3;
    const int s = blockIdx.x & 7;
    const int rbase = B * 256 + s * 32;

    if (t < 32) ldeg[t] = 0;
    __syncthreads();

    int n = cursor[B * CURSTRIDE];
    if (n > BCAP) n = BCAP;
    const u32* reg = breg + (size_t)B * BCAP;
    for (int i = t; i < n; i += 128) {
        u32 e = reg[i];
        if ((int)((e >> 21) & 7) == s) {
            int lr = (int)((e >> 16) & 31);
            u32 rk = atomicAdd(&ldeg[lr], 1u);
            if (rk < 64) lcsr[lr][rk] = (u16)(e & 0xFFFFu);
        }
    }
    __syncthreads();

    // top-k: thread t = lrow*4 + head (all 128 threads active)
    const int lrow = t >> 2;
    const int head = t & 3;
    const int row = rbase + lrow;

    u64 kl[TOPK];
    int cl[TOPK];
    #pragma unroll
    for (int i = 0; i < TOPK; ++i) { kl[i] = 0ull; cl[i] = 0; }

    int dgr = 0;
    if (row < NN) {
        dgr = (int)ldeg[lrow];
        if (dgr > 64) dgr = 64;
        // synthetic self-loop candidate (loses ties to any real slot)
        float v = s_j[(size_t)row * 4 + head];
        u32 b = __float_as_uint(v);
        u32 fk = (b & 0x80000000u) ? ~b : (b | 0x80000000u);
        kl[0] = ((u64)fk << 32) | (u32)(~(u32)(NE + row));
        cl[0] = row;
    }

    for (int j = 0; j < dgr; ++j) {
        int col = (int)lcsr[lrow][j];
        float v = s_j[(size_t)col * 4 + head];
        u32 b = __float_as_uint(v);
        u32 fk = (b & 0x80000000u) ? ~b : (b | 0x80000000u);
        u64 key = ((u64)fk << 32) | (u32)(~(u32)j);
        int cc = col;
        if (key > kl[TOPK - 1]) {
            #pragma unroll
            for (int i = 0; i < TOPK; ++i) {
                bool gt = key > kl[i];
                u64 tk = gt ? kl[i] : key;  kl[i] = gt ? key : kl[i];  key = tk;
                int tc = gt ? cl[i] : cc;   cl[i] = gt ? cc : cl[i];   cc = tc;
            }
        }
    }

    // softmax: fully thread-local (kl[0] is the max)
    {
        float si = (row < NN) ? s_i[(size_t)row * 4 + head] : 0.f;
        u32 fk = (u32)(kl[0] >> 32);
        u32 b = (fk & 0x80000000u) ? (fk ^ 0x80000000u) : ~fk;
        float vmax = __uint_as_float(b);
        float em = si + vmax;
        float m = (em >= 0.f) ? em : 0.2f * em;
        float al[TOPK];
        float denom = 0.f;
        #pragma unroll
        for (int i = 0; i < TOPK; ++i) {
            u32 fki = (u32)(kl[i] >> 32);
            u32 bi = (fki & 0x80000000u) ? (fki ^ 0x80000000u) : ~fki;
            float v = __uint_as_float(bi);
            float e = si + v;
            e = (e >= 0.f) ? e : 0.2f * e;
            float z = (kl[i] != 0ull) ? __expf(e - m) : 0.f;
            al[i] = z;
            denom += z;
        }
        float inv = 1.f / denom;
        #pragma unroll
        for (int i = 0; i < TOPK; ++i) {
            lal[t * 8 + i] = al[i] * inv;
            lcl[t * 8 + i] = (u16)cl[i];
        }
    }
    __syncthreads();

    // phase 2: 128 (row,head) pairs; lane=(pair q, float4 slot dq);
    // 8 independent 16B gathers in flight per lane, 1KB per load/store inst.
    const int lane = t & 63;
    const int wid = t >> 6;
    const int q = lane >> 3;
    const int dq = lane & 7;
    for (int g = wid; g < 16; g += 2) {
        const int p = g * 8 + q;          // pair 0..127 == lrow*4+hh
        const int r = rbase + (p >> 2);
        const int hh = p & 3;
        if (r < NN) {
            const int base = p * 8;
            float av[8]; int cv[8];
            #pragma unroll
            for (int k = 0; k < 8; ++k) { av[k] = lal[base + k]; cv[k] = (int)lcl[base + k]; }
            float4 a4 = make_float4(0.f, 0.f, 0.f, 0.f);
            #pragma unroll
            for (int k = 0; k < 8; ++k) {
                const float4 hv = *reinterpret_cast<const float4*>(
                    &hbuf[(size_t)cv[k] * 128 + hh * 32 + dq * 4]);
                a4.x += av[k] * hv.x;
                a4.y += av[k] * hv.y;
                a4.z += av[k] * hv.z;
                a4.w += av[k] * hv.w;
            }
            a4.x = (a4.x > 0.f) ? a4.x : expm1f(a4.x);
            a4.y = (a4.y > 0.f) ? a4.y : expm1f(a4.y);
            a4.z = (a4.z > 0.f) ? a4.z : expm1f(a4.z);
            a4.w = (a4.w > 0.f) ? a4.w : expm1f(a4.w);
            *reinterpret_cast<float4*>(&out[(size_t)r * 128 + hh * 32 + dq * 4]) = a4;
        }
    }
}

extern "C" void kernel_launch(void* const* d_in, const int* in_sizes, int n_in,
                              void* d_out, int out_size, void* d_ws, size_t ws_size,
                              hipStream_t stream) {
    const float* x   = (const float*)d_in[0];   // 50000x128 f32
    const float* W   = (const float*)d_in[1];   // 128x128  f32
    const float* att = (const float*)d_in[2];   // 4x64     f32
    const int*   ei  = (const int*)d_in[3];     // 2x800000 int32
    float* out = (float*)d_out;                 // 50000x128 f32

    u32* breg    = (u32*)d_ws;                  // 196*4608 u32 = 3.6 MB
    float* hbuf  = (float*)(breg + (size_t)NB * BCAP);  // 6.4M f32 = 25.6 MB
    float* s_i   = hbuf + 6400000;              // 200k f32
    float* s_j   = s_i + 200000;                // 200k f32
    int* cursor  = (int*)(s_j + 200000);        // 196*16 ints (64B-padded)
    // total ws: ~31 MB

    hipMemsetAsync(cursor, 0, NB * CURSTRIDE * sizeof(int), stream);
    gemm_k<<<GTILES, 256, 0, stream>>>(x, W, att, ei, hbuf, s_i, s_j, cursor, breg);
    rowsel_k<<<NB * 8, 128, 0, stream>>>(cursor, breg, s_i, s_j, hbuf, out);
}

// Round 13
// 174.186 us; speedup vs baseline: 13.0336x; 13.0336x over previous
//
#include <hip/hip_runtime.h>
#include <math.h>

typedef unsigned int u32;
typedef unsigned short u16;
typedef unsigned long long u64;

#define NN 50000
#define NE 800000
#define TOPK 8
#define NB 196           // coarse buckets of 256 rows (196*256 = 50176 >= NN)
#define BCAP 4608        // bucket capacity: mean 4082 + ~8 sigma
#define CURSTRIDE 16     // cursor padding: one counter per 64B line
#define GTILES 782       // ceil(NN/64) gemm tiles == edge chunks of 1024

// ---------------- gemm + edge partition fused (R11-measured version) ----------------
// Block b: gemm tile b (rows b*64..+63) AND edge chunk b (1024 edges).
// R12 lesson: do NOT restructure this staging loop (nested half-staging
// spilled 68->256 VGPR, 2.1GB scratch fetch, 42x slowdown). Reverted verbatim.
// Partition: LDS histogram over 196 buckets (LDS atomics), ONE padded global
// atomicAdd per (block,bucket); return parked in a register, consumed only at
// the tail scatter (no mid-kernel vmcnt stall). cursor[] zeroed by memset.
__global__ __launch_bounds__(256) void gemm_k(const float* __restrict__ x,
                                              const float* __restrict__ W,
                                              const float* __restrict__ att,
                                              const int* __restrict__ ei,
                                              float* __restrict__ hbuf,
                                              float* __restrict__ s_i,
                                              float* __restrict__ s_j,
                                              int* __restrict__ cursor,
                                              u32* __restrict__ breg) {
    __shared__ float xst[64][68];     // [k][r] transposed, 17.4 KB
    __shared__ float ws[64][128];     // [k][c], 32 KB
    __shared__ u32 cnt[NB];           // 784 B
    __shared__ u32 base[NB];          // 784 B   -> 51.7 KB total, 3 blocks/CU
    const int t = threadIdx.x;
    const int cx = t & 15;            // col group: cols cx*8..+7
    const int ry = t >> 4;            // row group: rows ry*4..+3
    const int rbase = blockIdx.x * 64;

    // edge chunk loads first (oldest vm ops -> retire before first use)
    const int e0 = blockIdx.x * 1024 + t * 4;
    const bool ev = e0 < NE;
    int4 er = make_int4(0, 0, 0, 0), ec = make_int4(0, 0, 0, 0);
    if (ev) {
        er = *reinterpret_cast<const int4*>(ei + e0);
        ec = *reinterpret_cast<const int4*>(ei + NE + e0);
    }
    if (t < NB) cnt[t] = 0;

    int bk[4];
    u32 lrk[4] = {0, 0, 0, 0};
    u32 myBase = 0;

    float acc[4][8];
    #pragma unroll
    for (int i = 0; i < 4; ++i)
        #pragma unroll
        for (int j = 0; j < 8; ++j) acc[i][j] = 0.f;

    for (int kk = 0; kk < 128; kk += 64) {
        if (kk) __syncthreads();
        #pragma unroll
        for (int rr = ry; rr < 64; rr += 16) {
            int gr = rbase + rr;
            float4 v = make_float4(0.f, 0.f, 0.f, 0.f);
            if (gr < NN)
                v = *reinterpret_cast<const float4*>(x + (size_t)gr * 128 + kk + cx * 4);
            xst[cx * 4 + 0][rr] = v.x;
            xst[cx * 4 + 1][rr] = v.y;
            xst[cx * 4 + 2][rr] = v.z;
            xst[cx * 4 + 3][rr] = v.w;
        }
        #pragma unroll
        for (int wk = t >> 5; wk < 64; wk += 8) {
            float4 v = *reinterpret_cast<const float4*>(W + (size_t)(kk + wk) * 128 + (t & 31) * 4);
            *reinterpret_cast<float4*>(&ws[wk][(t & 31) * 4]) = v;
        }
        __syncthreads();   // staging visible; also orders cnt zero / histogram / base

        if (kk == 0) {
            if (ev) {      // LDS histogram (edges retired by the staging drain)
                int rows[4] = {er.x, er.y, er.z, er.w};
                #pragma unroll
                for (int i = 0; i < 4; ++i) {
                    bk[i] = rows[i] >> 8;
                    lrk[i] = atomicAdd(&cnt[bk[i]], 1u);
                }
            }
        } else {
            // all histogram atomics complete (barrier above); issue cursor
            // atomics now — return consumed only after the epilogue.
            if (t < NB && cnt[t] > 0)
                myBase = (u32)atomicAdd(cursor + t * CURSTRIDE, (int)cnt[t]);
        }

        for (int k = 0; k < 64; ++k) {
            float4 xa = *reinterpret_cast<const float4*>(&xst[k][ry * 4]);
            float4 wa = *reinterpret_cast<const float4*>(&ws[k][cx * 8]);
            float4 wb = *reinterpret_cast<const float4*>(&ws[k][cx * 8 + 4]);
            float xv[4] = {xa.x, xa.y, xa.z, xa.w};
            float wv[8] = {wa.x, wa.y, wa.z, wa.w, wb.x, wb.y, wb.z, wb.w};
            #pragma unroll
            for (int i = 0; i < 4; ++i)
                #pragma unroll
                for (int j = 0; j < 8; ++j) acc[i][j] += xv[i] * wv[j];
        }
    }

    // epilogue: h + s_i/s_j (independent of the cursor atomics)
    const int head = cx >> 2;
    float aiv[8], ajv[8];
    #pragma unroll
    for (int j = 0; j < 8; ++j) {
        aiv[j] = att[head * 64 + (cx & 3) * 8 + j];
        ajv[j] = att[head * 64 + 32 + (cx & 3) * 8 + j];
    }
    #pragma unroll
    for (int i = 0; i < 4; ++i) {
        int gr = rbase + ry * 4 + i;
        float pi = 0.f, pj = 0.f;
        #pragma unroll
        for (int j = 0; j < 8; ++j) {
            pi += acc[i][j] * aiv[j];
            pj += acc[i][j] * ajv[j];
        }
        pi += __shfl_xor(pi, 1); pi += __shfl_xor(pi, 2);
        pj += __shfl_xor(pj, 1); pj += __shfl_xor(pj, 2);
        if (gr < NN) {
            float* dst = hbuf + (size_t)gr * 128 + cx * 8;
            *reinterpret_cast<float4*>(dst)     = make_float4(acc[i][0], acc[i][1], acc[i][2], acc[i][3]);
            *reinterpret_cast<float4*>(dst + 4) = make_float4(acc[i][4], acc[i][5], acc[i][6], acc[i][7]);
            if ((cx & 3) == 0) {
                s_i[(size_t)gr * 4 + head] = pi;
                s_j[(size_t)gr * 4 + head] = pj;
            }
        }
    }

    // publish bases (atomic returns have had the whole compute to land), scatter
    if (t < NB) base[t] = myBase;
    __syncthreads();
    if (ev) {
        int rows[4] = {er.x, er.y, er.z, er.w};
        int cols[4] = {ec.x, ec.y, ec.z, ec.w};
        #pragma unroll
        for (int i = 0; i < 4; ++i) {
            u32 pos = base[bk[i]] + lrk[i];
            if (pos < BCAP)
                breg[(size_t)bk[i] * BCAP + pos] = ((u32)(rows[i] & 255) << 16) | (u32)cols[i];
        }
    }
}

// ---------------- rowsel: LDS CSR build + top-k + softmax + aggregate ----------------
// 8 sub-blocks per bucket, 32 rows each, 128 threads -> grid 1568 (~6
// blocks/CU co-resident; R11's 784-block grid capped occupancy at 23%).
// All 128 threads active in top-k (1 thread per (row,head)). Block re-reads
// its bucket's packed edges (L2-hot) and filters its 32-row slice (bits 21-23).
// Correctness verified in R12 (passed, absmax 0.0039).
// Key = sortable-float(s_j)<<32 | ~slot; slot tie-break exact (distinct-col
// ties measure-zero, same-col output-invariant, self-loop last among equals).
__global__ __launch_bounds__(128) void rowsel_k(const int* __restrict__ cursor,
                                                const u32* __restrict__ breg,
                                                const float* __restrict__ s_i,
                                                const float* __restrict__ s_j,
                                                const float* __restrict__ hbuf,
                                                float* __restrict__ out) {
    __shared__ u16 lcsr[32][66];        // 4.2 KB (pad 66: banking)
    __shared__ u32 ldeg[32];
    __shared__ float lal[128 * 8];      // 4 KB
    __shared__ u16  lcl[128 * 8];       // 2 KB
    const int t = threadIdx.x;
    const int B = blockIdx.x >> 3;
    const int s = blockIdx.x & 7;
    const int rbase = B * 256 + s * 32;

    if (t < 32) ldeg[t] = 0;
    __syncthreads();

    int n = cursor[B * CURSTRIDE];
    if (n > BCAP) n = BCAP;
    const u32* reg = breg + (size_t)B * BCAP;
    for (int i = t; i < n; i += 128) {
        u32 e = reg[i];
        if ((int)((e >> 21) & 7) == s) {
            int lr = (int)((e >> 16) & 31);
            u32 rk = atomicAdd(&ldeg[lr], 1u);
            if (rk < 64) lcsr[lr][rk] = (u16)(e & 0xFFFFu);
        }
    }
    __syncthreads();

    // top-k: thread t = lrow*4 + head (all 128 threads active)
    const int lrow = t >> 2;
    const int head = t & 3;
    const int row = rbase + lrow;

    u64 kl[TOPK];
    int cl[TOPK];
    #pragma unroll
    for (int i = 0; i < TOPK; ++i) { kl[i] = 0ull; cl[i] = 0; }

    int dgr = 0;
    if (row < NN) {
        dgr = (int)ldeg[lrow];
        if (dgr > 64) dgr = 64;
        // synthetic self-loop candidate (loses ties to any real slot)
        float v = s_j[(size_t)row * 4 + head];
        u32 b = __float_as_uint(v);
        u32 fk = (b & 0x80000000u) ? ~b : (b | 0x80000000u);
        kl[0] = ((u64)fk << 32) | (u32)(~(u32)(NE + row));
        cl[0] = row;
    }

    for (int j = 0; j < dgr; ++j) {
        int col = (int)lcsr[lrow][j];
        float v = s_j[(size_t)col * 4 + head];
        u32 b = __float_as_uint(v);
        u32 fk = (b & 0x80000000u) ? ~b : (b | 0x80000000u);
        u64 key = ((u64)fk << 32) | (u32)(~(u32)j);
        int cc = col;
        if (key > kl[TOPK - 1]) {
            #pragma unroll
            for (int i = 0; i < TOPK; ++i) {
                bool gt = key > kl[i];
                u64 tk = gt ? kl[i] : key;  kl[i] = gt ? key : kl[i];  key = tk;
                int tc = gt ? cl[i] : cc;   cl[i] = gt ? cc : cl[i];   cc = tc;
            }
        }
    }

    // softmax: fully thread-local (kl[0] is the max)
    {
        float si = (row < NN) ? s_i[(size_t)row * 4 + head] : 0.f;
        u32 fk = (u32)(kl[0] >> 32);
        u32 b = (fk & 0x80000000u) ? (fk ^ 0x80000000u) : ~fk;
        float vmax = __uint_as_float(b);
        float em = si + vmax;
        float m = (em >= 0.f) ? em : 0.2f * em;
        float al[TOPK];
        float denom = 0.f;
        #pragma unroll
        for (int i = 0; i < TOPK; ++i) {
            u32 fki = (u32)(kl[i] >> 32);
            u32 bi = (fki & 0x80000000u) ? (fki ^ 0x80000000u) : ~fki;
            float v = __uint_as_float(bi);
            float e = si + v;
            e = (e >= 0.f) ? e : 0.2f * e;
            float z = (kl[i] != 0ull) ? __expf(e - m) : 0.f;
            al[i] = z;
            denom += z;
        }
        float inv = 1.f / denom;
        #pragma unroll
        for (int i = 0; i < TOPK; ++i) {
            lal[t * 8 + i] = al[i] * inv;
            lcl[t * 8 + i] = (u16)cl[i];
        }
    }
    __syncthreads();

    // phase 2: 128 (row,head) pairs; lane=(pair q, float4 slot dq);
    // 8 independent 16B gathers in flight per lane, 1KB per load/store inst.
    const int lane = t & 63;
    const int wid = t >> 6;
    const int q = lane >> 3;
    const int dq = lane & 7;
    for (int g = wid; g < 16; g += 2) {
        const int p = g * 8 + q;          // pair 0..127 == lrow*4+hh
        const int r = rbase + (p >> 2);
        const int hh = p & 3;
        if (r < NN) {
            const int base = p * 8;
            float av[8]; int cv[8];
            #pragma unroll
            for (int k = 0; k < 8; ++k) { av[k] = lal[base + k]; cv[k] = (int)lcl[base + k]; }
            float4 a4 = make_float4(0.f, 0.f, 0.f, 0.f);
            #pragma unroll
            for (int k = 0; k < 8; ++k) {
                const float4 hv = *reinterpret_cast<const float4*>(
                    &hbuf[(size_t)cv[k] * 128 + hh * 32 + dq * 4]);
                a4.x += av[k] * hv.x;
                a4.y += av[k] * hv.y;
                a4.z += av[k] * hv.z;
                a4.w += av[k] * hv.w;
            }
            a4.x = (a4.x > 0.f) ? a4.x : expm1f(a4.x);
            a4.y = (a4.y > 0.f) ? a4.y : expm1f(a4.y);
            a4.z = (a4.z > 0.f) ? a4.z : expm1f(a4.z);
            a4.w = (a4.w > 0.f) ? a4.w : expm1f(a4.w);
            *reinterpret_cast<float4*>(&out[(size_t)r * 128 + hh * 32 + dq * 4]) = a4;
        }
    }
}

extern "C" void kernel_launch(void* const* d_in, const int* in_sizes, int n_in,
                              void* d_out, int out_size, void* d_ws, size_t ws_size,
                              hipStream_t stream) {
    const float* x   = (const float*)d_in[0];   // 50000x128 f32
    const float* W   = (const float*)d_in[1];   // 128x128  f32
    const float* att = (const float*)d_in[2];   // 4x64     f32
    const int*   ei  = (const int*)d_in[3];     // 2x800000 int32
    float* out = (float*)d_out;                 // 50000x128 f32

    u32* breg    = (u32*)d_ws;                  // 196*4608 u32 = 3.6 MB
    float* hbuf  = (float*)(breg + (size_t)NB * BCAP);  // 6.4M f32 = 25.6 MB
    float* s_i   = hbuf + 6400000;              // 200k f32
    float* s_j   = s_i + 200000;                // 200k f32
    int* cursor  = (int*)(s_j + 200000);        // 196*16 ints (64B-padded)
    // total ws: ~31 MB

    hipMemsetAsync(cursor, 0, NB * CURSTRIDE * sizeof(int), stream);
    gemm_k<<<GTILES, 256, 0, stream>>>(x, W, att, ei, hbuf, s_i, s_j, cursor, breg);
    rowsel_k<<<NB * 8, 128, 0, stream>>>(cursor, breg, s_i, s_j, hbuf, out);
}

// Round 14
// 173.517 us; speedup vs baseline: 13.0838x; 1.0039x over previous
//
#include <hip/hip_runtime.h>
#include <math.h>

typedef unsigned int u32;
typedef unsigned short u16;
typedef unsigned long long u64;

#define NN 50000
#define NE 800000
#define TOPK 8
#define NB 196           // coarse buckets of 256 rows (196*256 = 50176 >= NN)
#define BCAP 4608        // bucket capacity: mean 4082 + ~8 sigma
#define CURSTRIDE 16     // cursor padding: one counter per 64B line
#define PBLOCKS 391      // ceil(NE/2048) partition blocks

// ---------------- gemm: h = x @ W + fused s_i/s_j (R0-proven 8x8 tile) ----------------
// BM=128, 8x8 register tile: 4 b128 LDS reads per 64 FMAs (the 4x8 tile paid
// 4 per 32 -> LDS-pipe-bound at ~31us; this halves LDS-pipe demand).
// LDS 66.6 KB -> 2 blocks/CU; grid 391 -> all blocks co-resident, no tail.
__global__ __launch_bounds__(256) void gemm_k(const float* __restrict__ x,
                                              const float* __restrict__ W,
                                              const float* __restrict__ att,
                                              float* __restrict__ hbuf,
                                              float* __restrict__ s_i,
                                              float* __restrict__ s_j) {
    __shared__ float xst[64][132];    // [k][r] transposed, 33.8 KB
    __shared__ float ws[64][128];     // [k][c], 32 KB
    const int t = threadIdx.x;
    const int cx = t & 15;            // col group: cols cx*8..+7
    const int ry = t >> 4;            // row group: rows ry*8..+7
    const int rbase = blockIdx.x * 128;

    float acc[8][8];
    #pragma unroll
    for (int i = 0; i < 8; ++i)
        #pragma unroll
        for (int j = 0; j < 8; ++j) acc[i][j] = 0.f;

    for (int kk = 0; kk < 128; kk += 64) {
        if (kk) __syncthreads();
        #pragma unroll
        for (int rr = ry; rr < 128; rr += 16) {
            int gr = rbase + rr;
            float4 v = make_float4(0.f, 0.f, 0.f, 0.f);
            if (gr < NN)
                v = *reinterpret_cast<const float4*>(x + (size_t)gr * 128 + kk + cx * 4);
            xst[cx * 4 + 0][rr] = v.x;
            xst[cx * 4 + 1][rr] = v.y;
            xst[cx * 4 + 2][rr] = v.z;
            xst[cx * 4 + 3][rr] = v.w;
        }
        #pragma unroll
        for (int wk = t >> 5; wk < 64; wk += 8) {
            float4 v = *reinterpret_cast<const float4*>(W + (size_t)(kk + wk) * 128 + (t & 31) * 4);
            *reinterpret_cast<float4*>(&ws[wk][(t & 31) * 4]) = v;
        }
        __syncthreads();

        for (int k = 0; k < 64; ++k) {
            float4 xa = *reinterpret_cast<const float4*>(&xst[k][ry * 8]);
            float4 xb = *reinterpret_cast<const float4*>(&xst[k][ry * 8 + 4]);
            float4 wa = *reinterpret_cast<const float4*>(&ws[k][cx * 8]);
            float4 wb = *reinterpret_cast<const float4*>(&ws[k][cx * 8 + 4]);
            float xv[8] = {xa.x, xa.y, xa.z, xa.w, xb.x, xb.y, xb.z, xb.w};
            float wv[8] = {wa.x, wa.y, wa.z, wa.w, wb.x, wb.y, wb.z, wb.w};
            #pragma unroll
            for (int i = 0; i < 8; ++i)
                #pragma unroll
                for (int j = 0; j < 8; ++j) acc[i][j] += xv[i] * wv[j];
        }
    }

    // epilogue: store h + fused s_i/s_j
    const int head = cx >> 2;
    float aiv[8], ajv[8];
    #pragma unroll
    for (int j = 0; j < 8; ++j) {
        aiv[j] = att[head * 64 + (cx & 3) * 8 + j];
        ajv[j] = att[head * 64 + 32 + (cx & 3) * 8 + j];
    }
    #pragma unroll
    for (int i = 0; i < 8; ++i) {
        int gr = rbase + ry * 8 + i;
        float pi = 0.f, pj = 0.f;
        #pragma unroll
        for (int j = 0; j < 8; ++j) {
            pi += acc[i][j] * aiv[j];
            pj += acc[i][j] * ajv[j];
        }
        pi += __shfl_xor(pi, 1); pi += __shfl_xor(pi, 2);
        pj += __shfl_xor(pj, 1); pj += __shfl_xor(pj, 2);
        if (gr < NN) {
            float* dst = hbuf + (size_t)gr * 128 + cx * 8;
            *reinterpret_cast<float4*>(dst)     = make_float4(acc[i][0], acc[i][1], acc[i][2], acc[i][3]);
            *reinterpret_cast<float4*>(dst + 4) = make_float4(acc[i][4], acc[i][5], acc[i][6], acc[i][7]);
            if ((cx & 3) == 0) {
                s_i[(size_t)gr * 4 + head] = pi;
                s_j[(size_t)gr * 4 + head] = pj;
            }
        }
    }
}

// ---------------- partition: edges -> 196 coarse buckets (R8/R9-measured) ----------------
// 2048 edges/block. LDS histogram (LDS atomics return local rank), ONE padded
// global atomicAdd per (block,bucket) -> ~77k global atomics (vs the 800k
// wall). Entry packs (row&255)<<16 | col (col < 2^16).
__global__ __launch_bounds__(256) void part_k(const int* __restrict__ ei,
                                              int* __restrict__ cursor,
                                              u32* __restrict__ breg) {
    __shared__ u32 cnt[NB];
    __shared__ u32 base[NB];
    const int t = threadIdx.x;
    if (t < NB) cnt[t] = 0;
    __syncthreads();

    const int e0 = blockIdx.x * 2048 + t * 8;   // NE%8==0 -> all-or-nothing
    const bool ev = e0 < NE;
    int rows[8], cols[8], bk[8];
    u32 lrk[8];
    if (ev) {
        int4 ra = *reinterpret_cast<const int4*>(ei + e0);
        int4 rb = *reinterpret_cast<const int4*>(ei + e0 + 4);
        int4 ca = *reinterpret_cast<const int4*>(ei + NE + e0);
        int4 cb = *reinterpret_cast<const int4*>(ei + NE + e0 + 4);
        rows[0] = ra.x; rows[1] = ra.y; rows[2] = ra.z; rows[3] = ra.w;
        rows[4] = rb.x; rows[5] = rb.y; rows[6] = rb.z; rows[7] = rb.w;
        cols[0] = ca.x; cols[1] = ca.y; cols[2] = ca.z; cols[3] = ca.w;
        cols[4] = cb.x; cols[5] = cb.y; cols[6] = cb.z; cols[7] = cb.w;
        #pragma unroll
        for (int i = 0; i < 8; ++i) {
            bk[i] = rows[i] >> 8;
            lrk[i] = atomicAdd(&cnt[bk[i]], 1u);
        }
    }
    __syncthreads();
    if (t < NB) base[t] = (cnt[t] > 0) ? (u32)atomicAdd(cursor + t * CURSTRIDE, (int)cnt[t]) : 0u;
    __syncthreads();
    if (ev) {
        #pragma unroll
        for (int i = 0; i < 8; ++i) {
            u32 pos = base[bk[i]] + lrk[i];
            if (pos < BCAP)
                breg[(size_t)bk[i] * BCAP + pos] = ((u32)(rows[i] & 255) << 16) | (u32)cols[i];
        }
    }
}

// ---------------- rowsel: LDS CSR build + top-k + softmax + aggregate ----------------
// R11-measured version (51.2 us) — 4 sub-blocks per bucket, 64 rows each,
// 256 threads. R13 lesson: finer splits regress (filter re-read scales with
// split factor; occupancy stays ~23% regardless — grid wasn't the limiter).
// Key = sortable-float(s_j)<<32 | ~slot; slot tie-break exact (distinct-col
// ties measure-zero, same-col output-invariant, self-loop last among equals).
__global__ __launch_bounds__(256) void rowsel_k(const int* __restrict__ cursor,
                                                const u32* __restrict__ breg,
                                                const float* __restrict__ s_i,
                                                const float* __restrict__ s_j,
                                                const float* __restrict__ hbuf,
                                                float* __restrict__ out) {
    __shared__ u16 lcsr[64][66];        // 8.25 KB (pad 66: banking)
    __shared__ u32 ldeg[64];
    __shared__ float lal[256 * 8];      // 8 KB
    __shared__ u16  lcl[256 * 8];       // 4 KB
    const int t = threadIdx.x;
    const int B = blockIdx.x >> 2;
    const int s = blockIdx.x & 3;
    const int rbase = B * 256 + s * 64;

    if (t < 64) ldeg[t] = 0;
    __syncthreads();

    int n = cursor[B * CURSTRIDE];
    if (n > BCAP) n = BCAP;
    const u32* reg = breg + (size_t)B * BCAP;
    for (int i = t; i < n; i += 256) {
        u32 e = reg[i];
        if ((int)(e >> 22) == s) {
            int lr = (int)((e >> 16) & 63);
            u32 rk = atomicAdd(&ldeg[lr], 1u);
            if (rk < 64) lcsr[lr][rk] = (u16)(e & 0xFFFFu);
        }
    }
    __syncthreads();

    // top-k: thread t = lrow*4 + head
    const int lrow = t >> 2;
    const int head = t & 3;
    const int row = rbase + lrow;

    u64 kl[TOPK];
    int cl[TOPK];
    #pragma unroll
    for (int i = 0; i < TOPK; ++i) { kl[i] = 0ull; cl[i] = 0; }

    int dgr = 0;
    if (row < NN) {
        dgr = (int)ldeg[lrow];
        if (dgr > 64) dgr = 64;
        // synthetic self-loop candidate (loses ties to any real slot)
        float v = s_j[(size_t)row * 4 + head];
        u32 b = __float_as_uint(v);
        u32 fk = (b & 0x80000000u) ? ~b : (b | 0x80000000u);
        kl[0] = ((u64)fk << 32) | (u32)(~(u32)(NE + row));
        cl[0] = row;
    }

    for (int j = 0; j < dgr; ++j) {
        int col = (int)lcsr[lrow][j];
        float v = s_j[(size_t)col * 4 + head];
        u32 b = __float_as_uint(v);
        u32 fk = (b & 0x80000000u) ? ~b : (b | 0x80000000u);
        u64 key = ((u64)fk << 32) | (u32)(~(u32)j);
        int cc = col;
        if (key > kl[TOPK - 1]) {
            #pragma unroll
            for (int i = 0; i < TOPK; ++i) {
                bool gt = key > kl[i];
                u64 tk = gt ? kl[i] : key;  kl[i] = gt ? key : kl[i];  key = tk;
                int tc = gt ? cl[i] : cc;   cl[i] = gt ? cc : cl[i];   cc = tc;
            }
        }
    }

    // softmax: fully thread-local (kl[0] is the max)
    {
        float si = (row < NN) ? s_i[(size_t)row * 4 + head] : 0.f;
        u32 fk = (u32)(kl[0] >> 32);
        u32 b = (fk & 0x80000000u) ? (fk ^ 0x80000000u) : ~fk;
        float vmax = __uint_as_float(b);
        float em = si + vmax;
        float m = (em >= 0.f) ? em : 0.2f * em;
        float al[TOPK];
        float denom = 0.f;
        #pragma unroll
        for (int i = 0; i < TOPK; ++i) {
            u32 fki = (u32)(kl[i] >> 32);
            u32 bi = (fki & 0x80000000u) ? (fki ^ 0x80000000u) : ~fki;
            float v = __uint_as_float(bi);
            float e = si + v;
            e = (e >= 0.f) ? e : 0.2f * e;
            float z = (kl[i] != 0ull) ? __expf(e - m) : 0.f;
            al[i] = z;
            denom += z;
        }
        float inv = 1.f / denom;
        #pragma unroll
        for (int i = 0; i < TOPK; ++i) {
            lal[t * 8 + i] = al[i] * inv;
            lcl[t * 8 + i] = (u16)cl[i];
        }
    }
    __syncthreads();

    // phase 2: 256 (row,head) pairs; lane=(pair q, float4 slot dq);
    // 8 independent 16B gathers in flight per lane, 1KB per load/store inst.
    const int lane = t & 63;
    const int wid = t >> 6;
    const int q = lane >> 3;
    const int dq = lane & 7;
    for (int g = wid; g < 32; g += 4) {
        const int p = g * 8 + q;          // pair 0..255 == lrow*4+hh
        const int r = rbase + (p >> 2);
        const int hh = p & 3;
        if (r < NN) {
            const int base = p * 8;
            float av[8]; int cv[8];
            #pragma unroll
            for (int k = 0; k < 8; ++k) { av[k] = lal[base + k]; cv[k] = (int)lcl[base + k]; }
            float4 a4 = make_float4(0.f, 0.f, 0.f, 0.f);
            #pragma unroll
            for (int k = 0; k < 8; ++k) {
                const float4 hv = *reinterpret_cast<const float4*>(
                    &hbuf[(size_t)cv[k] * 128 + hh * 32 + dq * 4]);
                a4.x += av[k] * hv.x;
                a4.y += av[k] * hv.y;
                a4.z += av[k] * hv.z;
                a4.w += av[k] * hv.w;
            }
            a4.x = (a4.x > 0.f) ? a4.x : expm1f(a4.x);
            a4.y = (a4.y > 0.f) ? a4.y : expm1f(a4.y);
            a4.z = (a4.z > 0.f) ? a4.z : expm1f(a4.z);
            a4.w = (a4.w > 0.f) ? a4.w : expm1f(a4.w);
            *reinterpret_cast<float4*>(&out[(size_t)r * 128 + hh * 32 + dq * 4]) = a4;
        }
    }
}

extern "C" void kernel_launch(void* const* d_in, const int* in_sizes, int n_in,
                              void* d_out, int out_size, void* d_ws, size_t ws_size,
                              hipStream_t stream) {
    const float* x   = (const float*)d_in[0];   // 50000x128 f32
    const float* W   = (const float*)d_in[1];   // 128x128  f32
    const float* att = (const float*)d_in[2];   // 4x64     f32
    const int*   ei  = (const int*)d_in[3];     // 2x800000 int32
    float* out = (float*)d_out;                 // 50000x128 f32

    u32* breg    = (u32*)d_ws;                  // 196*4608 u32 = 3.6 MB
    float* hbuf  = (float*)(breg + (size_t)NB * BCAP);  // 6.4M f32 = 25.6 MB
    float* s_i   = hbuf + 6400000;              // 200k f32
    float* s_j   = s_i + 200000;                // 200k f32
    int* cursor  = (int*)(s_j + 200000);        // 196*16 ints (64B-padded)
    // total ws: ~31 MB

    hipMemsetAsync(cursor, 0, NB * CURSTRIDE * sizeof(int), stream);
    gemm_k<<<(NN + 127) / 128, 256, 0, stream>>>(x, W, att, hbuf, s_i, s_j);
    part_k<<<PBLOCKS, 256, 0, stream>>>(ei, cursor, breg);
    rowsel_k<<<NB * 4, 256, 0, stream>>>(cursor, breg, s_i, s_j, hbuf, out);
}

// Round 15
// 163.959 us; speedup vs baseline: 13.8465x; 1.0583x over previous
//
#include <hip/hip_runtime.h>
#include <math.h>

typedef unsigned int u32;
typedef unsigned short u16;
typedef unsigned long long u64;

#define NN 50000
#define NE 800000
#define TOPK 8
#define NB 196           // coarse buckets of 256 rows (196*256 = 50176 >= NN)
#define BCAP 4608        // bucket capacity: mean 4082 + ~8 sigma
#define CURSTRIDE 16     // cursor padding: one counter per 64B line
#define GTILES 391       // ceil(NN/128) gemm tiles == edge chunks of 2048

// ---------------- gemm (8x8 tile) + edge partition fused ----------------
// Block b: gemm tile b (rows b*128..+127) AND edge chunk b (2048 edges).
// 8x8 register tile: 4 b128 LDS reads per 64 FMAs (halves LDS-pipe demand vs
// 4x8 — R13 analysis; R14 measured the 8x8 gemm below top-5). Staging loop
// kept VERBATIM from the measured kernel (R12 lesson: no restructure).
// Partition (R11-proven placement): edge loads issued first (retire under
// staging drain); LDS histogram after the kk=0 staging barrier; ONE padded
// global atomicAdd per (block,bucket) at the kk=64 barrier, return parked in
// a register; scatter at the kernel tail after base publish.
// LDS 67.4 KB -> 2 blocks/CU; grid 391 -> all blocks co-resident.
// cursor[] zeroed by prior memset.
__global__ __launch_bounds__(256) void gemm_k(const float* __restrict__ x,
                                              const float* __restrict__ W,
                                              const float* __restrict__ att,
                                              const int* __restrict__ ei,
                                              float* __restrict__ hbuf,
                                              float* __restrict__ s_i,
                                              float* __restrict__ s_j,
                                              int* __restrict__ cursor,
                                              u32* __restrict__ breg) {
    __shared__ float xst[64][132];    // [k][r] transposed, 33.8 KB
    __shared__ float ws[64][128];     // [k][c], 32 KB
    __shared__ u32 cnt[NB];           // 784 B
    __shared__ u32 base[NB];          // 784 B
    const int t = threadIdx.x;
    const int cx = t & 15;            // col group: cols cx*8..+7
    const int ry = t >> 4;            // row group: rows ry*8..+7
    const int rbase = blockIdx.x * 128;

    // edge chunk loads first (oldest vm ops -> retire under staging drain)
    const int e0 = blockIdx.x * 2048 + t * 8;   // NE%8==0 -> all-or-nothing
    const bool ev = e0 < NE;
    int4 ra = make_int4(0,0,0,0), rb = make_int4(0,0,0,0);
    int4 ca = make_int4(0,0,0,0), cb = make_int4(0,0,0,0);
    if (ev) {
        ra = *reinterpret_cast<const int4*>(ei + e0);
        rb = *reinterpret_cast<const int4*>(ei + e0 + 4);
        ca = *reinterpret_cast<const int4*>(ei + NE + e0);
        cb = *reinterpret_cast<const int4*>(ei + NE + e0 + 4);
    }
    if (t < NB) cnt[t] = 0;

    int bk[8];
    u32 lrk[8] = {0,0,0,0,0,0,0,0};
    u32 myBase = 0;

    float acc[8][8];
    #pragma unroll
    for (int i = 0; i < 8; ++i)
        #pragma unroll
        for (int j = 0; j < 8; ++j) acc[i][j] = 0.f;

    for (int kk = 0; kk < 128; kk += 64) {
        if (kk) __syncthreads();
        #pragma unroll
        for (int rr = ry; rr < 128; rr += 16) {
            int gr = rbase + rr;
            float4 v = make_float4(0.f, 0.f, 0.f, 0.f);
            if (gr < NN)
                v = *reinterpret_cast<const float4*>(x + (size_t)gr * 128 + kk + cx * 4);
            xst[cx * 4 + 0][rr] = v.x;
            xst[cx * 4 + 1][rr] = v.y;
            xst[cx * 4 + 2][rr] = v.z;
            xst[cx * 4 + 3][rr] = v.w;
        }
        #pragma unroll
        for (int wk = t >> 5; wk < 64; wk += 8) {
            float4 v = *reinterpret_cast<const float4*>(W + (size_t)(kk + wk) * 128 + (t & 31) * 4);
            *reinterpret_cast<float4*>(&ws[wk][(t & 31) * 4]) = v;
        }
        __syncthreads();   // staging visible; orders cnt zero / histogram / cursor

        if (kk == 0) {
            if (ev) {      // LDS histogram (edge loads retired by staging drain)
                int rows[8] = {ra.x, ra.y, ra.z, ra.w, rb.x, rb.y, rb.z, rb.w};
                #pragma unroll
                for (int i = 0; i < 8; ++i) {
                    bk[i] = rows[i] >> 8;
                    lrk[i] = atomicAdd(&cnt[bk[i]], 1u);
                }
            }
        } else {
            // histogram complete (barrier above); cursor atomics now —
            // return consumed only after the epilogue (no vmcnt consumer between).
            if (t < NB && cnt[t] > 0)
                myBase = (u32)atomicAdd(cursor + t * CURSTRIDE, (int)cnt[t]);
        }

        for (int k = 0; k < 64; ++k) {
            float4 xa = *reinterpret_cast<const float4*>(&xst[k][ry * 8]);
            float4 xb = *reinterpret_cast<const float4*>(&xst[k][ry * 8 + 4]);
            float4 wa = *reinterpret_cast<const float4*>(&ws[k][cx * 8]);
            float4 wb = *reinterpret_cast<const float4*>(&ws[k][cx * 8 + 4]);
            float xv[8] = {xa.x, xa.y, xa.z, xa.w, xb.x, xb.y, xb.z, xb.w};
            float wv[8] = {wa.x, wa.y, wa.z, wa.w, wb.x, wb.y, wb.z, wb.w};
            #pragma unroll
            for (int i = 0; i < 8; ++i)
                #pragma unroll
                for (int j = 0; j < 8; ++j) acc[i][j] += xv[i] * wv[j];
        }
    }

    // epilogue: h + s_i/s_j (independent of cursor atomics)
    const int head = cx >> 2;
    float aiv[8], ajv[8];
    #pragma unroll
    for (int j = 0; j < 8; ++j) {
        aiv[j] = att[head * 64 + (cx & 3) * 8 + j];
        ajv[j] = att[head * 64 + 32 + (cx & 3) * 8 + j];
    }
    #pragma unroll
    for (int i = 0; i < 8; ++i) {
        int gr = rbase + ry * 8 + i;
        float pi = 0.f, pj = 0.f;
        #pragma unroll
        for (int j = 0; j < 8; ++j) {
            pi += acc[i][j] * aiv[j];
            pj += acc[i][j] * ajv[j];
        }
        pi += __shfl_xor(pi, 1); pi += __shfl_xor(pi, 2);
        pj += __shfl_xor(pj, 1); pj += __shfl_xor(pj, 2);
        if (gr < NN) {
            float* dst = hbuf + (size_t)gr * 128 + cx * 8;
            *reinterpret_cast<float4*>(dst)     = make_float4(acc[i][0], acc[i][1], acc[i][2], acc[i][3]);
            *reinterpret_cast<float4*>(dst + 4) = make_float4(acc[i][4], acc[i][5], acc[i][6], acc[i][7]);
            if ((cx & 3) == 0) {
                s_i[(size_t)gr * 4 + head] = pi;
                s_j[(size_t)gr * 4 + head] = pj;
            }
        }
    }

    // publish bases (atomic returns landed during compute), then scatter
    if (t < NB) base[t] = myBase;
    __syncthreads();
    if (ev) {
        int rows[8] = {ra.x, ra.y, ra.z, ra.w, rb.x, rb.y, rb.z, rb.w};
        int cols[8] = {ca.x, ca.y, ca.z, ca.w, cb.x, cb.y, cb.z, cb.w};
        #pragma unroll
        for (int i = 0; i < 8; ++i) {
            u32 pos = base[bk[i]] + lrk[i];
            if (pos < BCAP)
                breg[(size_t)bk[i] * BCAP + pos] = ((u32)(rows[i] & 255) << 16) | (u32)cols[i];
        }
    }
}

// ---------------- rowsel: LDS CSR build + top-k + softmax + aggregate ----------------
// R11-measured version (51-52 us) — 4 sub-blocks per bucket, 64 rows each,
// 256 threads. R13 lesson: finer splits regress (filter re-read scales with
// split factor; occupancy ~23% regardless).
// Key = sortable-float(s_j)<<32 | ~slot; slot tie-break exact (distinct-col
// ties measure-zero, same-col output-invariant, self-loop last among equals).
__global__ __launch_bounds__(256) void rowsel_k(const int* __restrict__ cursor,
                                                const u32* __restrict__ breg,
                                                const float* __restrict__ s_i,
                                                const float* __restrict__ s_j,
                                                const float* __restrict__ hbuf,
                                                float* __restrict__ out) {
    __shared__ u16 lcsr[64][66];        // 8.25 KB (pad 66: banking)
    __shared__ u32 ldeg[64];
    __shared__ float lal[256 * 8];      // 8 KB
    __shared__ u16  lcl[256 * 8];       // 4 KB
    const int t = threadIdx.x;
    const int B = blockIdx.x >> 2;
    const int s = blockIdx.x & 3;
    const int rbase = B * 256 + s * 64;

    if (t < 64) ldeg[t] = 0;
    __syncthreads();

    int n = cursor[B * CURSTRIDE];
    if (n > BCAP) n = BCAP;
    const u32* reg = breg + (size_t)B * BCAP;
    for (int i = t; i < n; i += 256) {
        u32 e = reg[i];
        if ((int)(e >> 22) == s) {
            int lr = (int)((e >> 16) & 63);
            u32 rk = atomicAdd(&ldeg[lr], 1u);
            if (rk < 64) lcsr[lr][rk] = (u16)(e & 0xFFFFu);
        }
    }
    __syncthreads();

    // top-k: thread t = lrow*4 + head
    const int lrow = t >> 2;
    const int head = t & 3;
    const int row = rbase + lrow;

    u64 kl[TOPK];
    int cl[TOPK];
    #pragma unroll
    for (int i = 0; i < TOPK; ++i) { kl[i] = 0ull; cl[i] = 0; }

    int dgr = 0;
    if (row < NN) {
        dgr = (int)ldeg[lrow];
        if (dgr > 64) dgr = 64;
        // synthetic self-loop candidate (loses ties to any real slot)
        float v = s_j[(size_t)row * 4 + head];
        u32 b = __float_as_uint(v);
        u32 fk = (b & 0x80000000u) ? ~b : (b | 0x80000000u);
        kl[0] = ((u64)fk << 32) | (u32)(~(u32)(NE + row));
        cl[0] = row;
    }

    for (int j = 0; j < dgr; ++j) {
        int col = (int)lcsr[lrow][j];
        float v = s_j[(size_t)col * 4 + head];
        u32 b = __float_as_uint(v);
        u32 fk = (b & 0x80000000u) ? ~b : (b | 0x80000000u);
        u64 key = ((u64)fk << 32) | (u32)(~(u32)j);
        int cc = col;
        if (key > kl[TOPK - 1]) {
            #pragma unroll
            for (int i = 0; i < TOPK; ++i) {
                bool gt = key > kl[i];
                u64 tk = gt ? kl[i] : key;  kl[i] = gt ? key : kl[i];  key = tk;
                int tc = gt ? cl[i] : cc;   cl[i] = gt ? cc : cl[i];   cc = tc;
            }
        }
    }

    // softmax: fully thread-local (kl[0] is the max)
    {
        float si = (row < NN) ? s_i[(size_t)row * 4 + head] : 0.f;
        u32 fk = (u32)(kl[0] >> 32);
        u32 b = (fk & 0x80000000u) ? (fk ^ 0x80000000u) : ~fk;
        float vmax = __uint_as_float(b);
        float em = si + vmax;
        float m = (em >= 0.f) ? em : 0.2f * em;
        float al[TOPK];
        float denom = 0.f;
        #pragma unroll
        for (int i = 0; i < TOPK; ++i) {
            u32 fki = (u32)(kl[i] >> 32);
            u32 bi = (fki & 0x80000000u) ? (fki ^ 0x80000000u) : ~fki;
            float v = __uint_as_float(bi);
            float e = si + v;
            e = (e >= 0.f) ? e : 0.2f * e;
            float z = (kl[i] != 0ull) ? __expf(e - m) : 0.f;
            al[i] = z;
            denom += z;
        }
        float inv = 1.f / denom;
        #pragma unroll
        for (int i = 0; i < TOPK; ++i) {
            lal[t * 8 + i] = al[i] * inv;
            lcl[t * 8 + i] = (u16)cl[i];
        }
    }
    __syncthreads();

    // phase 2: 256 (row,head) pairs; lane=(pair q, float4 slot dq);
    // 8 independent 16B gathers in flight per lane, 1KB per load/store inst.
    const int lane = t & 63;
    const int wid = t >> 6;
    const int q = lane >> 3;
    const int dq = lane & 7;
    for (int g = wid; g < 32; g += 4) {
        const int p = g * 8 + q;          // pair 0..255 == lrow*4+hh
        const int r = rbase + (p >> 2);
        const int hh = p & 3;
        if (r < NN) {
            const int base = p * 8;
            float av[8]; int cv[8];
            #pragma unroll
            for (int k = 0; k < 8; ++k) { av[k] = lal[base + k]; cv[k] = (int)lcl[base + k]; }
            float4 a4 = make_float4(0.f, 0.f, 0.f, 0.f);
            #pragma unroll
            for (int k = 0; k < 8; ++k) {
                const float4 hv = *reinterpret_cast<const float4*>(
                    &hbuf[(size_t)cv[k] * 128 + hh * 32 + dq * 4]);
                a4.x += av[k] * hv.x;
                a4.y += av[k] * hv.y;
                a4.z += av[k] * hv.z;
                a4.w += av[k] * hv.w;
            }
            a4.x = (a4.x > 0.f) ? a4.x : expm1f(a4.x);
            a4.y = (a4.y > 0.f) ? a4.y : expm1f(a4.y);
            a4.z = (a4.z > 0.f) ? a4.z : expm1f(a4.z);
            a4.w = (a4.w > 0.f) ? a4.w : expm1f(a4.w);
            *reinterpret_cast<float4*>(&out[(size_t)r * 128 + hh * 32 + dq * 4]) = a4;
        }
    }
}

extern "C" void kernel_launch(void* const* d_in, const int* in_sizes, int n_in,
                              void* d_out, int out_size, void* d_ws, size_t ws_size,
                              hipStream_t stream) {
    const float* x   = (const float*)d_in[0];   // 50000x128 f32
    const float* W   = (const float*)d_in[1];   // 128x128  f32
    const float* att = (const float*)d_in[2];   // 4x64     f32
    const int*   ei  = (const int*)d_in[3];     // 2x800000 int32
    float* out = (float*)d_out;                 // 50000x128 f32

    u32* breg    = (u32*)d_ws;                  // 196*4608 u32 = 3.6 MB
    float* hbuf  = (float*)(breg + (size_t)NB * BCAP);  // 6.4M f32 = 25.6 MB
    float* s_i   = hbuf + 6400000;              // 200k f32
    float* s_j   = s_i + 200000;                // 200k f32
    int* cursor  = (int*)(s_j + 200000);        // 196*16 ints (64B-padded)
    // total ws: ~31 MB

    hipMemsetAsync(cursor, 0, NB * CURSTRIDE * sizeof(int), stream);
    gemm_k<<<GTILES, 256, 0, stream>>>(x, W, att, ei, hbuf, s_i, s_j, cursor, breg);
    rowsel_k<<<NB * 4, 256, 0, stream>>>(cursor, breg, s_i, s_j, hbuf, out);
}

// Round 16
// 160.062 us; speedup vs baseline: 14.1837x; 1.0244x over previous
//
#include <hip/hip_runtime.h>
#include <math.h>

typedef unsigned int u32;
typedef unsigned short u16;
typedef unsigned long long u64;

#define NN 50000
#define NE 800000
#define TOPK 8
#define NB 196           // coarse buckets of 256 rows (196*256 = 50176 >= NN)
#define BCAP 4608        // bucket capacity: mean 4082 + ~8 sigma
#define CURSTRIDE 16     // cursor padding: one counter per 64B line
#define GTILES 391       // ceil(NN/128) gemm tiles == edge chunks of 2048

__device__ __forceinline__ u32 f2bf(float a, float b) {
    // pack two f32 -> two bf16 (round-to-nearest-even), b in high half
    u32 ua = __float_as_uint(a);
    u32 ub = __float_as_uint(b);
    ua = (ua + 0x7FFFu + ((ua >> 16) & 1u)) >> 16;
    ub = (ub + 0x7FFFu + ((ub >> 16) & 1u)) >> 16;
    return (ub << 16) | (ua & 0xFFFFu);
}

// ---------------- gemm (8x8 tile) + edge partition fused ----------------
// Block b: gemm tile b (rows b*128..+127) AND edge chunk b (2048 edges).
// Staging/inner loop verbatim from the R15-measured kernel (R12 lesson).
// h stored as bf16 (RNE): halves rowsel's gather bytes + gemm's h-write.
// s_i/s_j computed from f32 accumulators (selection keys unchanged).
// Partition: edge loads first; LDS histogram after kk=0 staging barrier; ONE
// padded global atomicAdd per (block,bucket) at kk=64 barrier (return parked
// in a register); scatter at tail. cursor[] zeroed by prior memset.
__global__ __launch_bounds__(256) void gemm_k(const float* __restrict__ x,
                                              const float* __restrict__ W,
                                              const float* __restrict__ att,
                                              const int* __restrict__ ei,
                                              u16* __restrict__ hbuf,
                                              float* __restrict__ s_i,
                                              float* __restrict__ s_j,
                                              int* __restrict__ cursor,
                                              u32* __restrict__ breg) {
    __shared__ float xst[64][132];    // [k][r] transposed, 33.8 KB
    __shared__ float ws[64][128];     // [k][c], 32 KB
    __shared__ u32 cnt[NB];           // 784 B
    __shared__ u32 base[NB];          // 784 B
    const int t = threadIdx.x;
    const int cx = t & 15;            // col group: cols cx*8..+7
    const int ry = t >> 4;            // row group: rows ry*8..+7
    const int rbase = blockIdx.x * 128;

    // edge chunk loads first (oldest vm ops -> retire under staging drain)
    const int e0 = blockIdx.x * 2048 + t * 8;   // NE%8==0 -> all-or-nothing
    const bool ev = e0 < NE;
    int4 ra = make_int4(0,0,0,0), rb = make_int4(0,0,0,0);
    int4 ca = make_int4(0,0,0,0), cb = make_int4(0,0,0,0);
    if (ev) {
        ra = *reinterpret_cast<const int4*>(ei + e0);
        rb = *reinterpret_cast<const int4*>(ei + e0 + 4);
        ca = *reinterpret_cast<const int4*>(ei + NE + e0);
        cb = *reinterpret_cast<const int4*>(ei + NE + e0 + 4);
    }
    if (t < NB) cnt[t] = 0;

    int bk[8];
    u32 lrk[8] = {0,0,0,0,0,0,0,0};
    u32 myBase = 0;

    float acc[8][8];
    #pragma unroll
    for (int i = 0; i < 8; ++i)
        #pragma unroll
        for (int j = 0; j < 8; ++j) acc[i][j] = 0.f;

    for (int kk = 0; kk < 128; kk += 64) {
        if (kk) __syncthreads();
        #pragma unroll
        for (int rr = ry; rr < 128; rr += 16) {
            int gr = rbase + rr;
            float4 v = make_float4(0.f, 0.f, 0.f, 0.f);
            if (gr < NN)
                v = *reinterpret_cast<const float4*>(x + (size_t)gr * 128 + kk + cx * 4);
            xst[cx * 4 + 0][rr] = v.x;
            xst[cx * 4 + 1][rr] = v.y;
            xst[cx * 4 + 2][rr] = v.z;
            xst[cx * 4 + 3][rr] = v.w;
        }
        #pragma unroll
        for (int wk = t >> 5; wk < 64; wk += 8) {
            float4 v = *reinterpret_cast<const float4*>(W + (size_t)(kk + wk) * 128 + (t & 31) * 4);
            *reinterpret_cast<float4*>(&ws[wk][(t & 31) * 4]) = v;
        }
        __syncthreads();   // staging visible; orders cnt zero / histogram / cursor

        if (kk == 0) {
            if (ev) {      // LDS histogram (edge loads retired by staging drain)
                int rows[8] = {ra.x, ra.y, ra.z, ra.w, rb.x, rb.y, rb.z, rb.w};
                #pragma unroll
                for (int i = 0; i < 8; ++i) {
                    bk[i] = rows[i] >> 8;
                    lrk[i] = atomicAdd(&cnt[bk[i]], 1u);
                }
            }
        } else {
            // histogram complete (barrier above); cursor atomics now —
            // return consumed only after the epilogue.
            if (t < NB && cnt[t] > 0)
                myBase = (u32)atomicAdd(cursor + t * CURSTRIDE, (int)cnt[t]);
        }

        for (int k = 0; k < 64; ++k) {
            float4 xa = *reinterpret_cast<const float4*>(&xst[k][ry * 8]);
            float4 xb = *reinterpret_cast<const float4*>(&xst[k][ry * 8 + 4]);
            float4 wa = *reinterpret_cast<const float4*>(&ws[k][cx * 8]);
            float4 wb = *reinterpret_cast<const float4*>(&ws[k][cx * 8 + 4]);
            float xv[8] = {xa.x, xa.y, xa.z, xa.w, xb.x, xb.y, xb.z, xb.w};
            float wv[8] = {wa.x, wa.y, wa.z, wa.w, wb.x, wb.y, wb.z, wb.w};
            #pragma unroll
            for (int i = 0; i < 8; ++i)
                #pragma unroll
                for (int j = 0; j < 8; ++j) acc[i][j] += xv[i] * wv[j];
        }
    }

    // epilogue: h (bf16) + s_i/s_j (f32; independent of cursor atomics)
    const int head = cx >> 2;
    float aiv[8], ajv[8];
    #pragma unroll
    for (int j = 0; j < 8; ++j) {
        aiv[j] = att[head * 64 + (cx & 3) * 8 + j];
        ajv[j] = att[head * 64 + 32 + (cx & 3) * 8 + j];
    }
    #pragma unroll
    for (int i = 0; i < 8; ++i) {
        int gr = rbase + ry * 8 + i;
        float pi = 0.f, pj = 0.f;
        #pragma unroll
        for (int j = 0; j < 8; ++j) {
            pi += acc[i][j] * aiv[j];
            pj += acc[i][j] * ajv[j];
        }
        pi += __shfl_xor(pi, 1); pi += __shfl_xor(pi, 2);
        pj += __shfl_xor(pj, 1); pj += __shfl_xor(pj, 2);
        if (gr < NN) {
            uint4 hv;
            hv.x = f2bf(acc[i][0], acc[i][1]);
            hv.y = f2bf(acc[i][2], acc[i][3]);
            hv.z = f2bf(acc[i][4], acc[i][5]);
            hv.w = f2bf(acc[i][6], acc[i][7]);
            *reinterpret_cast<uint4*>(hbuf + (size_t)gr * 128 + cx * 8) = hv;
            if ((cx & 3) == 0) {
                s_i[(size_t)gr * 4 + head] = pi;
                s_j[(size_t)gr * 4 + head] = pj;
            }
        }
    }

    // publish bases (atomic returns landed during compute), then scatter
    if (t < NB) base[t] = myBase;
    __syncthreads();
    if (ev) {
        int rows[8] = {ra.x, ra.y, ra.z, ra.w, rb.x, rb.y, rb.z, rb.w};
        int cols[8] = {ca.x, ca.y, ca.z, ca.w, cb.x, cb.y, cb.z, cb.w};
        #pragma unroll
        for (int i = 0; i < 8; ++i) {
            u32 pos = base[bk[i]] + lrk[i];
            if (pos < BCAP)
                breg[(size_t)bk[i] * BCAP + pos] = ((u32)(rows[i] & 255) << 16) | (u32)cols[i];
        }
    }
}

// ---------------- rowsel: LDS CSR build + top-k + softmax + aggregate ----------------
// R11-measured structure (4 sub-blocks/bucket, 64 rows, 256 threads).
// Phase 2 adapted to bf16 hbuf: 4 lanes/pair, each lane loads 8 bf16 (16B)
// per neighbor -> half the gather bytes and load instructions of the f32
// version, same 8-deep MLP. Key = sortable-float(s_j)<<32 | ~slot (exact).
__global__ __launch_bounds__(256) void rowsel_k(const int* __restrict__ cursor,
                                                const u32* __restrict__ breg,
                                                const float* __restrict__ s_i,
                                                const float* __restrict__ s_j,
                                                const u16* __restrict__ hbuf,
                                                float* __restrict__ out) {
    __shared__ u16 lcsr[64][66];        // 8.25 KB (pad 66: banking)
    __shared__ u32 ldeg[64];
    __shared__ float lal[256 * 8];      // 8 KB
    __shared__ u16  lcl[256 * 8];       // 4 KB
    const int t = threadIdx.x;
    const int B = blockIdx.x >> 2;
    const int s = blockIdx.x & 3;
    const int rbase = B * 256 + s * 64;

    if (t < 64) ldeg[t] = 0;
    __syncthreads();

    int n = cursor[B * CURSTRIDE];
    if (n > BCAP) n = BCAP;
    const u32* reg = breg + (size_t)B * BCAP;
    for (int i = t; i < n; i += 256) {
        u32 e = reg[i];
        if ((int)(e >> 22) == s) {
            int lr = (int)((e >> 16) & 63);
            u32 rk = atomicAdd(&ldeg[lr], 1u);
            if (rk < 64) lcsr[lr][rk] = (u16)(e & 0xFFFFu);
        }
    }
    __syncthreads();

    // top-k: thread t = lrow*4 + head
    const int lrow = t >> 2;
    const int head = t & 3;
    const int row = rbase + lrow;

    u64 kl[TOPK];
    int cl[TOPK];
    #pragma unroll
    for (int i = 0; i < TOPK; ++i) { kl[i] = 0ull; cl[i] = 0; }

    int dgr = 0;
    if (row < NN) {
        dgr = (int)ldeg[lrow];
        if (dgr > 64) dgr = 64;
        // synthetic self-loop candidate (loses ties to any real slot)
        float v = s_j[(size_t)row * 4 + head];
        u32 b = __float_as_uint(v);
        u32 fk = (b & 0x80000000u) ? ~b : (b | 0x80000000u);
        kl[0] = ((u64)fk << 32) | (u32)(~(u32)(NE + row));
        cl[0] = row;
    }

    for (int j = 0; j < dgr; ++j) {
        int col = (int)lcsr[lrow][j];
        float v = s_j[(size_t)col * 4 + head];
        u32 b = __float_as_uint(v);
        u32 fk = (b & 0x80000000u) ? ~b : (b | 0x80000000u);
        u64 key = ((u64)fk << 32) | (u32)(~(u32)j);
        int cc = col;
        if (key > kl[TOPK - 1]) {
            #pragma unroll
            for (int i = 0; i < TOPK; ++i) {
                bool gt = key > kl[i];
                u64 tk = gt ? kl[i] : key;  kl[i] = gt ? key : kl[i];  key = tk;
                int tc = gt ? cl[i] : cc;   cl[i] = gt ? cc : cl[i];   cc = tc;
            }
        }
    }

    // softmax: fully thread-local (kl[0] is the max)
    {
        float si = (row < NN) ? s_i[(size_t)row * 4 + head] : 0.f;
        u32 fk = (u32)(kl[0] >> 32);
        u32 b = (fk & 0x80000000u) ? (fk ^ 0x80000000u) : ~fk;
        float vmax = __uint_as_float(b);
        float em = si + vmax;
        float m = (em >= 0.f) ? em : 0.2f * em;
        float al[TOPK];
        float denom = 0.f;
        #pragma unroll
        for (int i = 0; i < TOPK; ++i) {
            u32 fki = (u32)(kl[i] >> 32);
            u32 bi = (fki & 0x80000000u) ? (fki ^ 0x80000000u) : ~fki;
            float v = __uint_as_float(bi);
            float e = si + v;
            e = (e >= 0.f) ? e : 0.2f * e;
            float z = (kl[i] != 0ull) ? __expf(e - m) : 0.f;
            al[i] = z;
            denom += z;
        }
        float inv = 1.f / denom;
        #pragma unroll
        for (int i = 0; i < TOPK; ++i) {
            lal[t * 8 + i] = al[i] * inv;
            lcl[t * 8 + i] = (u16)cl[i];
        }
    }
    __syncthreads();

    // phase 2: 256 (row,head) pairs; 16 pairs per wave-iter, 4 lanes/pair.
    // lane = q*4+dq: pair q, 16B slot dq (8 bf16). 8 independent 16B gathers
    // in flight per lane; unpack bf16->f32 and FMA; 2 float4 stores per lane.
    const int lane = t & 63;
    const int wid = t >> 6;
    const int q = lane >> 2;
    const int dq = lane & 3;
    for (int g = wid; g < 16; g += 4) {
        const int p = g * 16 + q;         // pair 0..255 == lrow*4+hh
        const int r = rbase + (p >> 2);
        const int hh = p & 3;
        if (r < NN) {
            const int base = p * 8;
            float av[8]; int cv[8];
            #pragma unroll
            for (int k = 0; k < 8; ++k) { av[k] = lal[base + k]; cv[k] = (int)lcl[base + k]; }
            float f[8];
            #pragma unroll
            for (int j = 0; j < 8; ++j) f[j] = 0.f;
            #pragma unroll
            for (int k = 0; k < 8; ++k) {
                const uint4 hv = *reinterpret_cast<const uint4*>(
                    hbuf + (size_t)cv[k] * 128 + hh * 32 + dq * 8);
                const float a = av[k];
                f[0] += a * __uint_as_float((hv.x & 0xFFFFu) << 16);
                f[1] += a * __uint_as_float(hv.x & 0xFFFF0000u);
                f[2] += a * __uint_as_float((hv.y & 0xFFFFu) << 16);
                f[3] += a * __uint_as_float(hv.y & 0xFFFF0000u);
                f[4] += a * __uint_as_float((hv.z & 0xFFFFu) << 16);
                f[5] += a * __uint_as_float(hv.z & 0xFFFF0000u);
                f[6] += a * __uint_as_float((hv.w & 0xFFFFu) << 16);
                f[7] += a * __uint_as_float(hv.w & 0xFFFF0000u);
            }
            #pragma unroll
            for (int j = 0; j < 8; ++j) f[j] = (f[j] > 0.f) ? f[j] : expm1f(f[j]);
            float* dst = out + (size_t)r * 128 + hh * 32 + dq * 8;
            *reinterpret_cast<float4*>(dst)     = make_float4(f[0], f[1], f[2], f[3]);
            *reinterpret_cast<float4*>(dst + 4) = make_float4(f[4], f[5], f[6], f[7]);
        }
    }
}

extern "C" void kernel_launch(void* const* d_in, const int* in_sizes, int n_in,
                              void* d_out, int out_size, void* d_ws, size_t ws_size,
                              hipStream_t stream) {
    const float* x   = (const float*)d_in[0];   // 50000x128 f32
    const float* W   = (const float*)d_in[1];   // 128x128  f32
    const float* att = (const float*)d_in[2];   // 4x64     f32
    const int*   ei  = (const int*)d_in[3];     // 2x800000 int32
    float* out = (float*)d_out;                 // 50000x128 f32

    u32* breg    = (u32*)d_ws;                  // 196*4608 u32 = 3.6 MB
    u16* hbuf    = (u16*)(breg + (size_t)NB * BCAP);    // 6.4M bf16 = 12.8 MB
    float* s_i   = (float*)(hbuf + 6400000);    // 200k f32
    float* s_j   = s_i + 200000;                // 200k f32
    int* cursor  = (int*)(s_j + 200000);        // 196*16 ints (64B-padded)
    // total ws: ~18 MB

    hipMemsetAsync(cursor, 0, NB * CURSTRIDE * sizeof(int), stream);
    gemm_k<<<GTILES, 256, 0, stream>>>(x, W, att, ei, hbuf, s_i, s_j, cursor, breg);
    rowsel_k<<<NB * 4, 256, 0, stream>>>(cursor, breg, s_i, s_j, hbuf, out);
}